// Round 3
// baseline (280.779 us; speedup 1.0000x reference)
//
#include <hip/hip_runtime.h>

// Zero-phase bandpass FIR = one 8191-tap correlation with the kernel
// autocorrelation g, as an implicit-Toeplitz MFMA GEMM.
//   out[t] = sum_s g[s] * xe[t + s],  g = autocorr(k) (bf16-hi only)
// Round 3: occupancy fix. Q-split x2 (atomicAdd combine into zeroed d_out),
// 1-wave blocks (2048 blocks = 8/CU), compile-time trip counts (QSTEPS
// padded 281->288, A-table 312 chunks), SC=16 LDS chunks (14.5 KB/block).

#define T_LEN   131072
#define XE_LEN  139776            // uint4 reads reach 17455 < 17472
#define XE_U4   (XE_LEN / 8)
#define NCHUNK  312               // A chunks: p in [-24, 288), P = p + 24
#define QSTEPS  288               // padded to 18 chunks of SC=16
#define SC      16                // Q-steps per LDS chunk
#define NCH_Q   18
#define CHS     9                 // chunks per Q-half (blockIdx.z)
#define CW      113               // staged uint4 slots/row (94 used, +pad)

typedef float  f32x4  __attribute__((ext_vector_type(4)));
typedef __bf16 bf16x8 __attribute__((ext_vector_type(8)));

// ---------- ws layout (bytes) ----------
#define WS_KZ   0                 // 12288 floats (zero-padded k)
#define WS_G    49152             // 8192 floats  (autocorrelation)
#define WS_AHI  81920             // 312*512 bf16 Toeplitz frags = 319488 B
#define WS_XE   401408            // 32*139776 bf16 padded signal
#define WS_END  9347072

// K0: kz[m] = zero-padded k; also zero g (memset fused away)
__global__ void k_build_kz(const float* __restrict__ k, float* __restrict__ kz,
                           float* __restrict__ g) {
  int m = blockIdx.x * 256 + threadIdx.x;
  if (m < 12288) {
    int i = m - 4096;
    kz[m] = (i >= 0 && i < 4096) ? k[i] : 0.0f;
  }
  if (m < 8192) g[m] = 0.0f;
}

// K1: g[s] += partial over i-chunk; grid (32, 16), g pre-zeroed.
__global__ void k_autocorr(const float* __restrict__ k,
                           const float* __restrict__ kz,
                           float* __restrict__ g) {
  int s = blockIdx.x * 256 + threadIdx.x;
  int i0 = blockIdx.y * 256;
  const float* kk  = k + i0;
  const float* kzs = kz + (8191 - s) + i0;
  float a0 = 0.f, a1 = 0.f, a2 = 0.f, a3 = 0.f;
  #pragma unroll 8
  for (int i = 0; i < 256; i += 4) {
    a0 = fmaf(kk[i],     kzs[i],     a0);
    a1 = fmaf(kk[i + 1], kzs[i + 1], a1);
    a2 = fmaf(kk[i + 2], kzs[i + 2], a2);
    a3 = fmaf(kk[i + 3], kzs[i + 3], a3);
  }
  atomicAdd(&g[s], (a0 + a1) + (a2 + a3));
}

// K2: Toeplitz A fragments, fragment-ordered (chunk P, lane l, 8 bf16).
// A_p[i][k] = gpad[32p + k - i], lane l: i = l&15, k = (l>>4)*8 + jj.
__global__ void k_build_afrag(const float* __restrict__ g,
                              __bf16* __restrict__ Ahi) {
  int P = blockIdx.x;              // 0..311
  int t = threadIdx.x;
  int l = t >> 2;
  int jj0 = (t & 3) * 2;
  int q = l >> 4, i = l & 15;
  int p = P - 24;
  #pragma unroll
  for (int u = 0; u < 2; ++u) {
    int jj = jj0 + u;
    int s = 32 * p + 8 * q + jj - i;
    float val = (s >= 0 && s <= 8190) ? g[s] : 0.0f;
    Ahi[P * 512 + l * 8 + jj] = (__bf16)val;
  }
}

// K3: xe[row][w] = bf16( X(w - 4095) ): reflect in [-2048, T+2048), else 0
__global__ void k_build_xe(const float* __restrict__ x, __bf16* __restrict__ xe) {
  int idx = blockIdx.x * 256 + threadIdx.x;
  int row = blockIdx.y;
  if (idx >= XE_LEN) return;
  int v = idx - 4095;
  float val = 0.0f;
  if (v >= -2048 && v < T_LEN + 2048) {
    int v2 = v < 0 ? -v : v;
    v2 = v2 >= T_LEN ? 2 * T_LEN - 2 - v2 : v2;
    val = x[(size_t)row * T_LEN + v2];
  }
  xe[(size_t)row * XE_LEN + idx] = (__bf16)val;
}

// Main: 1 wave/block, 4 rows x 4 time-tiles (1024 outputs), half the Q-range
// (blockIdx.z). Grid (128, 8, 2) = 2048 blocks = 8/CU. B double-buffered in
// LDS (SC=16 Qs/chunk), A from L1 (binding pipe at ~82%). Partial sums
// combined with atomicAdd into memset-zeroed out.
__global__ __launch_bounds__(64, 2) void k_fir_mfma(
    const uint4* __restrict__ xeu, const uint4* __restrict__ Ahi,
    float* __restrict__ out) {
  __shared__ uint4 sb[2][4 * CW];

  const int l   = threadIdx.x;
  const int q   = l >> 4;
  const int n   = l & 15;
  const int t0  = blockIdx.x << 10;          // 1024 outputs per block
  const int rbase = blockIdx.y * 4;
  const int chBeg = blockIdx.z * CHS;
  const int lofs = q + 2 * n;                // uint4 offset within B window

  // staging: 16 threads per row, 7 uint4s each (covers 112 >= 94 needed)
  const int srow = l >> 4;
  const int c0   = l & 15;
  const uint4* gsrc = xeu + (size_t)(rbase + srow) * XE_U4 + (t0 >> 3);

  f32x4 acc[4][4];                           // [row r][tile mt]
  #pragma unroll
  for (int r = 0; r < 4; ++r)
    #pragma unroll
    for (int m = 0; m < 4; ++m) acc[r][m] = (f32x4){0.f, 0.f, 0.f, 0.f};

  // stage first chunk
  #pragma unroll
  for (int u = 0; u < 7; ++u)
    sb[0][srow * CW + c0 + (u << 4)] = gsrc[(chBeg << 6) + c0 + (u << 4)];
  __syncthreads();

  uint4 pre[7];
  #pragma unroll
  for (int cc = 0; cc < CHS; ++cc) {
    const int ch = chBeg + cc;
    const bool more = (cc + 1) < CHS;
    if (more) {
      const uint4* gch = gsrc + ((ch + 1) << 6);
      #pragma unroll
      for (int u = 0; u < 7; ++u) pre[u] = gch[c0 + (u << 4)];
    }

    const uint4* bw = &sb[cc & 1][lofs];
    #pragma unroll 4
    for (int Qr = 0; Qr < SC; ++Qr) {
      const int Q = (ch << 4) + Qr;
      uint4 ub0 = bw[0 * CW + 4 * Qr];
      uint4 ub1 = bw[1 * CW + 4 * Qr];
      uint4 ub2 = bw[2 * CW + 4 * Qr];
      uint4 ub3 = bw[3 * CW + 4 * Qr];
      bf16x8 B0 = __builtin_bit_cast(bf16x8, ub0);
      bf16x8 B1 = __builtin_bit_cast(bf16x8, ub1);
      bf16x8 B2 = __builtin_bit_cast(bf16x8, ub2);
      bf16x8 B3 = __builtin_bit_cast(bf16x8, ub3);
      #pragma unroll
      for (int mt = 0; mt < 4; ++mt) {
        bf16x8 A = __builtin_bit_cast(bf16x8, Ahi[(Q + 24 - 8 * mt) * 64 + l]);
        acc[0][mt] = __builtin_amdgcn_mfma_f32_16x16x32_bf16(A, B0, acc[0][mt], 0, 0, 0);
        acc[1][mt] = __builtin_amdgcn_mfma_f32_16x16x32_bf16(A, B1, acc[1][mt], 0, 0, 0);
        acc[2][mt] = __builtin_amdgcn_mfma_f32_16x16x32_bf16(A, B2, acc[2][mt], 0, 0, 0);
        acc[3][mt] = __builtin_amdgcn_mfma_f32_16x16x32_bf16(A, B3, acc[3][mt], 0, 0, 0);
      }
    }

    if (more) {
      uint4* dst = &sb[(cc + 1) & 1][srow * CW];
      #pragma unroll
      for (int u = 0; u < 7; ++u) dst[c0 + (u << 4)] = pre[u];
    }
    __syncthreads();
  }

  // C/D layout: col(j)=lane&15, row(i)=(lane>>4)*4+reg; t = t0+256mt+i+16j.
  const int co = (q << 2) + (n << 4);
  #pragma unroll
  for (int r = 0; r < 4; ++r) {
    float* dst = out + (size_t)(rbase + r) * T_LEN + t0 + co;
    #pragma unroll
    for (int mt = 0; mt < 4; ++mt) {
      #pragma unroll
      for (int e = 0; e < 4; ++e)
        atomicAdd(dst + (mt << 8) + e, acc[r][mt][e]);
    }
  }
}

extern "C" void kernel_launch(void* const* d_in, const int* in_sizes, int n_in,
                              void* d_out, int out_size, void* d_ws, size_t ws_size,
                              hipStream_t stream) {
  const float* x = (const float*)d_in[0];
  const float* k = (const float*)d_in[1];
  float* out = (float*)d_out;
  char* ws = (char*)d_ws;
  if (ws_size < (size_t)WS_END) return;

  float*  kz  = (float*)(ws + WS_KZ);
  float*  g   = (float*)(ws + WS_G);
  __bf16* Ahi = (__bf16*)(ws + WS_AHI);
  __bf16* xe  = (__bf16*)(ws + WS_XE);

  k_build_kz<<<dim3(48), dim3(256), 0, stream>>>(k, kz, g);
  k_autocorr<<<dim3(32, 16), dim3(256), 0, stream>>>(k, kz, g);
  k_build_afrag<<<dim3(NCHUNK), dim3(256), 0, stream>>>(g, Ahi);
  k_build_xe<<<dim3(XE_LEN / 256, 32), dim3(256), 0, stream>>>(x, xe);
  hipMemsetAsync(out, 0, (size_t)32 * T_LEN * sizeof(float), stream);
  k_fir_mfma<<<dim3(T_LEN / 1024, 8, 2), dim3(64), 0, stream>>>(
      (const uint4*)xe, (const uint4*)Ahi, out);
}

// Round 4
// 213.229 us; speedup vs baseline: 1.3168x; 1.3168x over previous
//
#include <hip/hip_runtime.h>

// Zero-phase bandpass FIR = one 8191-tap correlation with the kernel
// autocorrelation g, as an implicit-Toeplitz MFMA GEMM.
//   out[t] = sum_s g[s] * xe[t + s],  g = autocorr(k) (bf16, hi only)
// Round 4: block = 4 waves = 4 Q-quarters of ONE 8-row x 1024-t tile.
// No global atomics (LDS phased combine), no main-loop barriers (wave-
// private LDS B-buffer + register prefetch), R=8/T=4 (A L2 traffic halved),
// outer chunk loop NOT unrolled (I-cache). Grid 512 = 2 blocks/CU.

#define T_LEN   131072
#define XE_LEN  139776
#define XE_U4   (XE_LEN / 8)      // 17472 uint4 per row
#define NCHUNK  312               // A chunks: table P in [0,312), p = P-24
#define QSTEPS  288               // 4 quarters x 72
#define QQ      72                // Q-steps per wave
#define SCH     8                 // Q-steps per LDS chunk
#define NCH     9                 // chunks per wave
#define CW      74                // uint4 slots/row/chunk (66 used; 74 skews banks)

typedef float  f32x4  __attribute__((ext_vector_type(4)));
typedef __bf16 bf16x8 __attribute__((ext_vector_type(8)));

// ---------- ws layout (bytes) ----------
#define WS_KZ   0                 // 12288 floats (zero-padded k)
#define WS_G    49152             // 8192 floats  (autocorrelation)
#define WS_AHI  81920             // 312*512 bf16 Toeplitz frags = 319488 B
#define WS_XE   401408            // 32*139776 bf16 padded signal
#define WS_END  9347072

// K0: kz[m] = zero-padded k; also zero g
__global__ void k_build_kz(const float* __restrict__ k, float* __restrict__ kz,
                           float* __restrict__ g) {
  int m = blockIdx.x * 256 + threadIdx.x;
  if (m < 12288) {
    int i = m - 4096;
    kz[m] = (i >= 0 && i < 4096) ? k[i] : 0.0f;
  }
  if (m < 8192) g[m] = 0.0f;
}

// K1: g[s] += partial over 256-long i-chunk; grid (32, 16), float4 loads.
__global__ void k_autocorr(const float* __restrict__ k,
                           const float* __restrict__ kz,
                           float* __restrict__ g) {
  int s = blockIdx.x * 256 + threadIdx.x;
  int i0 = blockIdx.y * 256;
  const float* kk  = k + i0;
  const float* kzs = kz + (8191 - s) + i0;   // 4-B aligned only
  float a0 = 0.f, a1 = 0.f, a2 = 0.f, a3 = 0.f;
  #pragma unroll 4
  for (int i = 0; i < 256; i += 4) {
    float4 kv = *(const float4*)(kk + i);
    float4 zv;
    __builtin_memcpy(&zv, kzs + i, 16);
    a0 = fmaf(kv.x, zv.x, a0);
    a1 = fmaf(kv.y, zv.y, a1);
    a2 = fmaf(kv.z, zv.z, a2);
    a3 = fmaf(kv.w, zv.w, a3);
  }
  atomicAdd(&g[s], (a0 + a1) + (a2 + a3));
}

// K2: Toeplitz A fragments, fragment-ordered (chunk P, lane l, 8 bf16).
// A_p[i][k] = gpad[32p + k - i], lane l: i = l&15, k = (l>>4)*8 + jj.
__global__ void k_build_afrag(const float* __restrict__ g,
                              __bf16* __restrict__ Ahi) {
  int P = blockIdx.x;
  int t = threadIdx.x;
  int l = t >> 2;
  int jj0 = (t & 3) * 2;
  int q = l >> 4, i = l & 15;
  int p = P - 24;
  #pragma unroll
  for (int u = 0; u < 2; ++u) {
    int jj = jj0 + u;
    int s = 32 * p + 8 * q + jj - i;
    float val = (s >= 0 && s <= 8190) ? g[s] : 0.0f;
    Ahi[P * 512 + l * 8 + jj] = (__bf16)val;
  }
}

// K3: xe[row][w] = bf16( X(w-4095) ), reflect in [-2048, T+2048), else 0.
// 8 elements / thread, single uint4 store.
__global__ void k_build_xe(const float* __restrict__ x, __bf16* __restrict__ xe) {
  int e0 = (blockIdx.x * 256 + threadIdx.x) * 8;
  int row = blockIdx.y;
  if (e0 >= XE_LEN) return;
  const float* xr = x + (size_t)row * T_LEN;
  int v0 = e0 - 4095;
  bf16x8 outv;
  if (v0 >= 0 && v0 <= T_LEN - 8) {          // interior fast path
    float4 f0, f1;
    __builtin_memcpy(&f0, xr + v0, 16);
    __builtin_memcpy(&f1, xr + v0 + 4, 16);
    outv[0] = (__bf16)f0.x; outv[1] = (__bf16)f0.y;
    outv[2] = (__bf16)f0.z; outv[3] = (__bf16)f0.w;
    outv[4] = (__bf16)f1.x; outv[5] = (__bf16)f1.y;
    outv[6] = (__bf16)f1.z; outv[7] = (__bf16)f1.w;
  } else {
    #pragma unroll
    for (int u = 0; u < 8; ++u) {
      int v = v0 + u;
      float val = 0.0f;
      if (v >= -2048 && v < T_LEN + 2048) {
        int v2 = v < 0 ? -v : v;
        v2 = v2 >= T_LEN ? 2 * T_LEN - 2 - v2 : v2;
        val = xr[v2];
      }
      outv[u] = (__bf16)val;
    }
  }
  ((uint4*)(xe + (size_t)row * XE_LEN))[e0 >> 3] =
      __builtin_bit_cast(uint4, outv);
}

// Main: 256 threads = 4 waves, each wave = one Q-quarter (72 Q-steps) of the
// same 8-row x 1024-t tile. Per Q: 4 A-loads (L2), 8 B ds_reads, 32 MFMAs.
// B: wave-private LDS chunk (SCH=8 Qs) refilled via register prefetch; no
// __syncthreads in the main loop. Combine: 4 phased disjoint-mt LDS passes.
__global__ __launch_bounds__(256, 2) void k_fir_mfma(
    const uint4* __restrict__ xeu, const uint4* __restrict__ Ahi,
    float* __restrict__ out) {
  __shared__ uint4 sbB[4 * 8 * CW];          // 37888 B; reused as C (32 KB)

  const int tid = threadIdx.x;
  const int w   = tid >> 6;                  // wave = Q-quarter
  const int l   = tid & 63;
  const int q   = l >> 4;
  const int n   = l & 15;
  const int t0  = blockIdx.x << 10;          // 1024 outputs per block
  const int rbase = blockIdx.y << 3;         // 8 rows per block
  const int Qbeg  = w * QQ;
  const int lofs  = q + 2 * n;               // uint4 offset in B window

  // staging: lane l covers row sr = l>>3, cols cb + 8u (u<9, covers 0..71)
  const int sr = l >> 3;
  const int cb = l & 7;
  const uint4* gsrc = xeu + (size_t)(rbase + sr) * XE_U4 + (t0 >> 3)
                      + 4 * Qbeg + cb;
  uint4* sbw  = sbB + w * (8 * CW);
  uint4* sdst = sbw + sr * CW + cb;

  f32x4 acc[8][4];
  #pragma unroll
  for (int r = 0; r < 8; ++r)
    #pragma unroll
    for (int m = 0; m < 4; ++m) acc[r][m] = (f32x4){0.f, 0.f, 0.f, 0.f};

  uint4 pre[9];
  #pragma unroll
  for (int u = 0; u < 9; ++u) pre[u] = gsrc[u << 3];
  #pragma unroll
  for (int u = 0; u < 9; ++u) sdst[u * 8] = pre[u];

  for (int ch = 0; ch < NCH; ++ch) {         // NOT unrolled (I-cache)
    if (ch + 1 < NCH) {
      const uint4* gn = gsrc + ((ch + 1) << 5);   // +32 uint4 per chunk
      #pragma unroll
      for (int u = 0; u < 9; ++u) pre[u] = gn[u << 3];
    }
    const uint4* bw = sbw + lofs;
    #pragma unroll 2
    for (int Qr = 0; Qr < SCH; ++Qr) {
      const int Q = Qbeg + (ch << 3) + Qr;
      bf16x8 A[4];
      #pragma unroll
      for (int mt = 0; mt < 4; ++mt)
        A[mt] = __builtin_bit_cast(bf16x8, Ahi[(Q + 24 - 8 * mt) * 64 + l]);
      #pragma unroll
      for (int r = 0; r < 8; ++r) {
        bf16x8 B = __builtin_bit_cast(bf16x8, bw[r * CW + 4 * Qr]);
        #pragma unroll
        for (int mt = 0; mt < 4; ++mt)
          acc[r][mt] =
              __builtin_amdgcn_mfma_f32_16x16x32_bf16(A[mt], B, acc[r][mt], 0, 0, 0);
      }
    }
    if (ch + 1 < NCH) {
      #pragma unroll
      for (int u = 0; u < 9; ++u) sdst[u * 8] = pre[u];
    }
  }

  // ---- combine 4 Q-quarter partials in LDS (phased, disjoint mt slices) ----
  __syncthreads();
  float* C = (float*)sbB;                    // 8 rows x 1024 t
  const int co = (q << 2) + (n << 4);        // C/D: col=n, row=(q*4+reg)
  #pragma unroll
  for (int ph = 0; ph < 4; ++ph) {
    const int mt = (w + ph) & 3;
    float* cp = C + (mt << 8) + co;
    if (ph == 0) {
      #pragma unroll
      for (int r = 0; r < 8; ++r)
        *(f32x4*)(cp + (r << 10)) = acc[r][mt];
    } else {
      #pragma unroll
      for (int r = 0; r < 8; ++r) {
        f32x4 v = *(f32x4*)(cp + (r << 10));
        v += acc[r][mt];
        *(f32x4*)(cp + (r << 10)) = v;
      }
    }
    __syncthreads();
  }

  // ---- coalesced store: 2048 f32x4, 256 threads x 8 ----
  #pragma unroll
  for (int u = 0; u < 8; ++u) {
    f32x4 v = ((f32x4*)C)[tid + (u << 8)];
    *(f32x4*)(out + (size_t)(rbase + u) * T_LEN + t0 + (tid << 2)) = v;
  }
}

extern "C" void kernel_launch(void* const* d_in, const int* in_sizes, int n_in,
                              void* d_out, int out_size, void* d_ws, size_t ws_size,
                              hipStream_t stream) {
  const float* x = (const float*)d_in[0];
  const float* k = (const float*)d_in[1];
  float* out = (float*)d_out;
  char* ws = (char*)d_ws;
  if (ws_size < (size_t)WS_END) return;

  float*  kz  = (float*)(ws + WS_KZ);
  float*  g   = (float*)(ws + WS_G);
  __bf16* Ahi = (__bf16*)(ws + WS_AHI);
  __bf16* xe  = (__bf16*)(ws + WS_XE);

  k_build_kz<<<dim3(48), dim3(256), 0, stream>>>(k, kz, g);
  k_autocorr<<<dim3(32, 16), dim3(256), 0, stream>>>(k, kz, g);
  k_build_afrag<<<dim3(NCHUNK), dim3(256), 0, stream>>>(g, Ahi);
  k_build_xe<<<dim3((XE_LEN / 8 + 255) / 256, 32), dim3(256), 0, stream>>>(x, xe);
  k_fir_mfma<<<dim3(T_LEN / 1024, 4), dim3(256), 0, stream>>>(
      (const uint4*)xe, (const uint4*)Ahi, out);
}

// Round 5
// 167.123 us; speedup vs baseline: 1.6801x; 1.2759x over previous
//
#include <hip/hip_runtime.h>

// Zero-phase bandpass FIR = one 8191-tap correlation with the kernel
// autocorrelation g, as an implicit-Toeplitz MFMA GEMM.
//   out[t] = sum_s g[s] * xe[t + s],  g = autocorr(k) (bf16, hi only)
// Round 5: spill fix. B staged via __builtin_amdgcn_global_load_lds
// (width 16, async, zero staging VGPRs), wave-private double-buffered LDS
// chunks drained by manual s_waitcnt vmcnt(0); no barriers in main loop.
// 4 waves = 4 Q-quarters of one 8-row x 1024-t tile; LDS phased combine.

#define T_LEN   131072
#define XE_LEN  139776
#define XE_U4   (XE_LEN / 8)      // 17472 uint4 per row
#define NCHUNK  312               // A chunks: table P in [0,312), p = P-24
#define QSTEPS  288               // 4 quarters x 72
#define QQ      72                // Q-steps per wave
#define SCH     8                 // Q-steps per LDS chunk
#define NCH     9                 // chunks per wave
#define CW      64                // uint4 slots/row/chunk (max read 61)

typedef float  f32x4  __attribute__((ext_vector_type(4)));
typedef __bf16 bf16x8 __attribute__((ext_vector_type(8)));

// ---------- ws layout (bytes) ----------
#define WS_KZ   0                 // 12288 floats (zero-padded k)
#define WS_G    49152             // 8192 floats  (autocorrelation)
#define WS_AHI  81920             // 312*512 bf16 Toeplitz frags = 319488 B
#define WS_XE   401408            // 32*139776 bf16 padded signal
#define WS_END  9347072

__device__ __forceinline__ void gload_lds16(const uint4* g, uint4* lds) {
  __builtin_amdgcn_global_load_lds(
      (const __attribute__((address_space(1))) unsigned int*)g,
      (__attribute__((address_space(3))) unsigned int*)lds, 16, 0, 0);
}

// K0: kz[m] = zero-padded k; also zero g
__global__ void k_build_kz(const float* __restrict__ k, float* __restrict__ kz,
                           float* __restrict__ g) {
  int m = blockIdx.x * 256 + threadIdx.x;
  if (m < 12288) {
    int i = m - 4096;
    kz[m] = (i >= 0 && i < 4096) ? k[i] : 0.0f;
  }
  if (m < 8192) g[m] = 0.0f;
}

// K1: g[s] += partial over 256-long i-chunk; grid (32, 16).
__global__ void k_autocorr(const float* __restrict__ k,
                           const float* __restrict__ kz,
                           float* __restrict__ g) {
  int s = blockIdx.x * 256 + threadIdx.x;
  int i0 = blockIdx.y * 256;
  const float* kk  = k + i0;
  const float* kzs = kz + (8191 - s) + i0;   // 4-B aligned only
  float a0 = 0.f, a1 = 0.f, a2 = 0.f, a3 = 0.f;
  #pragma unroll 4
  for (int i = 0; i < 256; i += 4) {
    float4 kv = *(const float4*)(kk + i);
    float4 zv;
    __builtin_memcpy(&zv, kzs + i, 16);
    a0 = fmaf(kv.x, zv.x, a0);
    a1 = fmaf(kv.y, zv.y, a1);
    a2 = fmaf(kv.z, zv.z, a2);
    a3 = fmaf(kv.w, zv.w, a3);
  }
  atomicAdd(&g[s], (a0 + a1) + (a2 + a3));
}

// K2: Toeplitz A fragments, fragment-ordered (chunk P, lane l, 8 bf16).
// A_p[i][k] = gpad[32p + k - i], lane l: i = l&15, k = (l>>4)*8 + jj.
__global__ void k_build_afrag(const float* __restrict__ g,
                              __bf16* __restrict__ Ahi) {
  int P = blockIdx.x;
  int t = threadIdx.x;
  int l = t >> 2;
  int jj0 = (t & 3) * 2;
  int q = l >> 4, i = l & 15;
  int p = P - 24;
  #pragma unroll
  for (int u = 0; u < 2; ++u) {
    int jj = jj0 + u;
    int s = 32 * p + 8 * q + jj - i;
    float val = (s >= 0 && s <= 8190) ? g[s] : 0.0f;
    Ahi[P * 512 + l * 8 + jj] = (__bf16)val;
  }
}

// K3: xe[row][w] = bf16( X(w-4095) ), reflect in [-2048, T+2048), else 0.
__global__ void k_build_xe(const float* __restrict__ x, __bf16* __restrict__ xe) {
  int e0 = (blockIdx.x * 256 + threadIdx.x) * 8;
  int row = blockIdx.y;
  if (e0 >= XE_LEN) return;
  const float* xr = x + (size_t)row * T_LEN;
  int v0 = e0 - 4095;
  bf16x8 outv;
  if (v0 >= 0 && v0 <= T_LEN - 8) {
    float4 f0, f1;
    __builtin_memcpy(&f0, xr + v0, 16);
    __builtin_memcpy(&f1, xr + v0 + 4, 16);
    outv[0] = (__bf16)f0.x; outv[1] = (__bf16)f0.y;
    outv[2] = (__bf16)f0.z; outv[3] = (__bf16)f0.w;
    outv[4] = (__bf16)f1.x; outv[5] = (__bf16)f1.y;
    outv[6] = (__bf16)f1.z; outv[7] = (__bf16)f1.w;
  } else {
    #pragma unroll
    for (int u = 0; u < 8; ++u) {
      int v = v0 + u;
      float val = 0.0f;
      if (v >= -2048 && v < T_LEN + 2048) {
        int v2 = v < 0 ? -v : v;
        v2 = v2 >= T_LEN ? 2 * T_LEN - 2 - v2 : v2;
        val = xr[v2];
      }
      outv[u] = (__bf16)val;
    }
  }
  ((uint4*)(xe + (size_t)row * XE_LEN))[e0 >> 3] =
      __builtin_bit_cast(uint4, outv);
}

// Main: 256 threads = 4 waves; wave w computes Q-quarter w (72 Q-steps) of
// one 8-row x 1024-t tile. Per Q: 4 A global loads (L1/L2), 8 ds_read_b128,
// 32 MFMAs. B staged chunk-wise (SCH=8 Qs) by async global_load_lds into a
// wave-private double buffer; manual vmcnt drain, no __syncthreads in loop.
// Grid (128, 4) = 512 blocks = 2/CU (LDS-limited), 16 waves/CU.
__global__ __launch_bounds__(256, 2) void k_fir_mfma(
    const uint4* __restrict__ xeu, const uint4* __restrict__ Ahi,
    float* __restrict__ out) {
  __shared__ uint4 sbB[4096];      // 64 KB: wave*1024 + buf*512 + row*64

  const int tid = threadIdx.x;
  const int w   = tid >> 6;                  // wave = Q-quarter
  const int l   = tid & 63;
  const int q   = l >> 4;
  const int n   = l & 15;
  const int t0  = blockIdx.x << 10;          // 1024 outputs per block
  const int rbase = blockIdx.y << 3;         // 8 rows per block
  const int Qbeg  = w * QQ;
  const int lofs  = q + 2 * n;               // uint4 offset in B window

  // per-lane global base for staging (lane l covers uint4 slot l of a row)
  const uint4* gbase = xeu + (size_t)rbase * XE_U4 + (t0 >> 3) + 4 * Qbeg + l;
  uint4* sw = sbB + (w << 10);

  f32x4 acc[8][4];
  #pragma unroll
  for (int r = 0; r < 8; ++r)
    #pragma unroll
    for (int m = 0; m < 4; ++m) acc[r][m] = (f32x4){0.f, 0.f, 0.f, 0.f};

  // stage chunk 0 into buf 0
  #pragma unroll
  for (int r = 0; r < 8; ++r)
    gload_lds16(gbase + (size_t)r * XE_U4, sw + (r << 6));
  asm volatile("s_waitcnt vmcnt(0)" ::: "memory");

  int buf = 0;
  for (int ch = 0; ch < NCH; ++ch) {         // NOT unrolled (I-cache)
    if (ch + 1 < NCH) {                      // async-stage next chunk
      uint4* dst = sw + ((buf ^ 1) << 9);
      const uint4* src = gbase + ((ch + 1) << 5);
      #pragma unroll
      for (int r = 0; r < 8; ++r)
        gload_lds16(src + (size_t)r * XE_U4, dst + (r << 6));
    }

    const uint4* bw = sw + (buf << 9) + lofs;
    #pragma unroll 2
    for (int Qr = 0; Qr < SCH; ++Qr) {
      const int Q = Qbeg + (ch << 3) + Qr;
      bf16x8 A[4];
      #pragma unroll
      for (int mt = 0; mt < 4; ++mt)
        A[mt] = __builtin_bit_cast(bf16x8, Ahi[(Q + 24 - 8 * mt) * 64 + l]);
      #pragma unroll
      for (int r = 0; r < 8; ++r) {
        bf16x8 B = __builtin_bit_cast(bf16x8, bw[(r << 6) + 4 * Qr]);
        #pragma unroll
        for (int mt = 0; mt < 4; ++mt)
          acc[r][mt] =
              __builtin_amdgcn_mfma_f32_16x16x32_bf16(A[mt], B, acc[r][mt], 0, 0, 0);
      }
    }

    if (ch + 1 < NCH) {
      asm volatile("s_waitcnt vmcnt(0)" ::: "memory");   // next buf ready
      buf ^= 1;
    }
  }

  // ---- combine 4 Q-quarter partials in LDS (phased, disjoint mt slices) ----
  __syncthreads();
  float* C = (float*)sbB;                    // 8 rows x 1024 t (32 KB)
  const int co = (q << 2) + (n << 4);        // C/D: col=n, row=(q*4+reg)
  #pragma unroll
  for (int ph = 0; ph < 4; ++ph) {
    const int mt = (w + ph) & 3;
    float* cp = C + (mt << 8) + co;
    if (ph == 0) {
      #pragma unroll
      for (int r = 0; r < 8; ++r)
        *(f32x4*)(cp + (r << 10)) = acc[r][mt];
    } else {
      #pragma unroll
      for (int r = 0; r < 8; ++r) {
        f32x4 v = *(f32x4*)(cp + (r << 10));
        v += acc[r][mt];
        *(f32x4*)(cp + (r << 10)) = v;
      }
    }
    __syncthreads();
  }

  // ---- coalesced store: 2048 f32x4, 256 threads x 8 ----
  #pragma unroll
  for (int u = 0; u < 8; ++u) {
    f32x4 v = ((f32x4*)C)[tid + (u << 8)];
    *(f32x4*)(out + (size_t)(rbase + u) * T_LEN + t0 + (tid << 2)) = v;
  }
}

extern "C" void kernel_launch(void* const* d_in, const int* in_sizes, int n_in,
                              void* d_out, int out_size, void* d_ws, size_t ws_size,
                              hipStream_t stream) {
  const float* x = (const float*)d_in[0];
  const float* k = (const float*)d_in[1];
  float* out = (float*)d_out;
  char* ws = (char*)d_ws;
  if (ws_size < (size_t)WS_END) return;

  float*  kz  = (float*)(ws + WS_KZ);
  float*  g   = (float*)(ws + WS_G);
  __bf16* Ahi = (__bf16*)(ws + WS_AHI);
  __bf16* xe  = (__bf16*)(ws + WS_XE);

  k_build_kz<<<dim3(48), dim3(256), 0, stream>>>(k, kz, g);
  k_autocorr<<<dim3(32, 16), dim3(256), 0, stream>>>(k, kz, g);
  k_build_afrag<<<dim3(NCHUNK), dim3(256), 0, stream>>>(g, Ahi);
  k_build_xe<<<dim3((XE_LEN / 8 + 255) / 256, 32), dim3(256), 0, stream>>>(x, xe);
  k_fir_mfma<<<dim3(T_LEN / 1024, 4), dim3(256), 0, stream>>>(
      (const uint4*)xe, (const uint4*)Ahi, out);
}